// Round 7
// baseline (240.088 us; speedup 1.0000x reference)
//
#include <hip/hip_runtime.h>
#include <hip/hip_fp16.h>

typedef _Float16 f16x4_t __attribute__((ext_vector_type(4)));
typedef _Float16 f16x8_t __attribute__((ext_vector_type(8)));
typedef float    f32x4_t __attribute__((ext_vector_type(4)));

#define GLDS16(gp, lp)                                                                   \
  __builtin_amdgcn_global_load_lds((const __attribute__((address_space(1))) void*)(gp),  \
                                   (__attribute__((address_space(3))) void*)(lp), 16, 0, 0)

constexpr int BB = 4, SS = 2048, DD = 1024, HH = 16, HDIM = 64;
constexpr int LOOKA = 64, LEFTC = 512;
constexpr int MROWS = BB * SS;   // 8192
constexpr int N3D = 3 * DD;      // 3072

// ---------------- f32 -> f16 convert (vectorized) ----------------
__global__ void cvt_kernel(const float* __restrict__ in, _Float16* __restrict__ out) {
  const int i = (blockIdx.x * 256 + threadIdx.x) * 4;
  const float4 v = *reinterpret_cast<const float4*>(in + i);
  f16x4_t o;
  o[0] = (_Float16)v.x; o[1] = (_Float16)v.y; o[2] = (_Float16)v.z; o[3] = (_Float16)v.w;
  *reinterpret_cast<f16x4_t*>(out + i) = o;
}

// ============ QKV GEMM: 256x256, BK=64, 8 waves, 4-phase pipeline ============
// RACE FIX vs round 6: ds_reads stay BEFORE the barrier (latency absorbed by
// barrier-wait), but the once-per-tile vmcnt(4) moves to phase 3 of the PREVIOUS
// tile, before its barrier. vmcnt is per-wave: only [wait -> barrier -> read]
// proves OTHER waves' staging landed. Ledger (2 loads/half, 1 half/phase,
// order ph0:B0(T+1) ph1:A1(T+1) ph2:A0(T+2) ph3:B1(T+2)):
//   at ph3(T) after staging, 12 in flight; vmcnt(4) lands the oldest 8
//   = ALL four halves of tile T+1; barrier => safe for T+1's reads.
__global__ __launch_bounds__(512, 1) void gemm_qkv8(const _Float16* __restrict__ A,
                                                    const _Float16* __restrict__ Bm,
                                                    const float* __restrict__ bias,
                                                    _Float16* __restrict__ Cout,
                                                    _Float16* __restrict__ vt) {
  constexpr int BK = 64, NT = 1024 / BK;  // 16 K-tiles
  __shared__ _Float16 Ash[2][2][128 * 64];
  __shared__ _Float16 Bsh[2][2][128 * 64];

  // bijective XCD-chunked swizzle: 384 blocks, 48 per XCD
  const int bid = blockIdx.x;
  const int nid = (bid & 7) * 48 + (bid >> 3);
  const int mb = nid / 12, nb = nid % 12;
  const size_t Mblk = (size_t)mb * 256, Nblk = (size_t)nb * 256;

  const int tid = threadIdx.x;
  const int w = tid >> 6, lane = tid & 63;
  const int lr = lane & 15, lg = lane >> 4;
  const int wr = w >> 2;   // 0..1 (M)
  const int wc = w & 3;    // 0..3 (N)

  // staging: region row = i*64 + w*8 + (lane>>3); global chunk = (lane&7)^(lane>>3)
  const int rw = w * 8 + (lane >> 3);
  const int cg = (lane & 7) ^ (lane >> 3);
  const _Float16* Ag = A + (Mblk + rw) * 1024 + cg * 8;
  const _Float16* Bg = Bm + (Nblk + rw) * 1024 + cg * 8;

  auto stageA = [&](int t, int h) {
    const int s = t & 1;
    const int kt = (t & (NT - 1)) * BK;  // wrap at tail (dummy prefetch, never read)
#pragma unroll
    for (int i = 0; i < 2; ++i)
      GLDS16(Ag + (size_t)(h * 128 + i * 64) * 1024 + kt,
             (char*)&Ash[s][h][0] + w * 1024 + i * 8192);
  };
  auto stageB = [&](int t, int h) {
    const int s = t & 1;
    const int kt = (t & (NT - 1)) * BK;
#pragma unroll
    for (int i = 0; i < 2; ++i)
      GLDS16(Bg + (size_t)(h * 128 + i * 64) * 1024 + kt,
             (char*)&Bsh[s][h][0] + w * 1024 + i * 8192);
  };

  f32x4_t acc[2][4][2][2] = {};  // [mh][mi4][nh][ni2]
  f16x8_t af[4][2], bf0[2][2], bf1[2][2];

  const int axr = (wr * 64 + lr) * 64;
  const int bxr = (wc * 32 + lr) * 64;
  const int c0 = (lg ^ (lr & 7)) * 8;
  const int c1 = ((4 + lg) ^ (lr & 7)) * 8;

  // prologue: tile 0's 4 halves (oldest 8 loads) + A0(1), B1(1); then wait+barrier
  stageA(0, 0);  // A0(0)
  stageB(0, 1);  // B1(0)
  stageB(0, 0);  // B0(0)
  stageA(0, 1);  // A1(0)
  stageA(1, 0);  // A0(1)
  stageB(1, 1);  // B1(1)
  asm volatile("s_waitcnt vmcnt(4)" ::: "memory");  // tile 0's 8 loads landed
  asm volatile("s_barrier" ::: "memory");

  for (int T = 0; T < NT; ++T) {
    const int s = T & 1;

    // ---------- phase 0: quadrant (0,0) ----------
#pragma unroll
    for (int m = 0; m < 4; ++m) {
      af[m][0] = *reinterpret_cast<const f16x8_t*>(&Ash[s][0][axr + m * 1024 + c0]);
      af[m][1] = *reinterpret_cast<const f16x8_t*>(&Ash[s][0][axr + m * 1024 + c1]);
    }
#pragma unroll
    for (int n = 0; n < 2; ++n) {
      bf0[n][0] = *reinterpret_cast<const f16x8_t*>(&Bsh[s][0][bxr + n * 1024 + c0]);
      bf0[n][1] = *reinterpret_cast<const f16x8_t*>(&Bsh[s][0][bxr + n * 1024 + c1]);
    }
    stageB(T + 1, 0);  // B0(T+1)
    asm volatile("s_barrier" ::: "memory");
    __builtin_amdgcn_s_setprio(1);
#pragma unroll
    for (int m = 0; m < 4; ++m)
#pragma unroll
      for (int n = 0; n < 2; ++n)
#pragma unroll
        for (int kk = 0; kk < 2; ++kk)
          acc[0][m][0][n] = __builtin_amdgcn_mfma_f32_16x16x32_f16(af[m][kk], bf0[n][kk], acc[0][m][0][n], 0, 0, 0);
    __builtin_amdgcn_s_setprio(0);

    // ---------- phase 1: quadrant (0,1) ----------
#pragma unroll
    for (int n = 0; n < 2; ++n) {
      bf1[n][0] = *reinterpret_cast<const f16x8_t*>(&Bsh[s][1][bxr + n * 1024 + c0]);
      bf1[n][1] = *reinterpret_cast<const f16x8_t*>(&Bsh[s][1][bxr + n * 1024 + c1]);
    }
    stageA(T + 1, 1);  // A1(T+1)
    asm volatile("s_barrier" ::: "memory");
    __builtin_amdgcn_s_setprio(1);
#pragma unroll
    for (int m = 0; m < 4; ++m)
#pragma unroll
      for (int n = 0; n < 2; ++n)
#pragma unroll
        for (int kk = 0; kk < 2; ++kk)
          acc[0][m][1][n] = __builtin_amdgcn_mfma_f32_16x16x32_f16(af[m][kk], bf1[n][kk], acc[0][m][1][n], 0, 0, 0);
    __builtin_amdgcn_s_setprio(0);

    // ---------- phase 2: quadrant (1,1) ----------
#pragma unroll
    for (int m = 0; m < 4; ++m) {
      af[m][0] = *reinterpret_cast<const f16x8_t*>(&Ash[s][1][axr + m * 1024 + c0]);
      af[m][1] = *reinterpret_cast<const f16x8_t*>(&Ash[s][1][axr + m * 1024 + c1]);
    }
    stageA(T + 2, 0);  // A0(T+2)
    asm volatile("s_barrier" ::: "memory");
    __builtin_amdgcn_s_setprio(1);
#pragma unroll
    for (int m = 0; m < 4; ++m)
#pragma unroll
      for (int n = 0; n < 2; ++n)
#pragma unroll
        for (int kk = 0; kk < 2; ++kk)
          acc[1][m][1][n] = __builtin_amdgcn_mfma_f32_16x16x32_f16(af[m][kk], bf1[n][kk], acc[1][m][1][n], 0, 0, 0);
    __builtin_amdgcn_s_setprio(0);

    // ---------- phase 3: quadrant (1,0) ---------- (frags already in regs)
    stageB(T + 2, 1);  // B1(T+2)
    asm volatile("s_waitcnt vmcnt(4)" ::: "memory");  // tile T+1's 4 halves landed
    asm volatile("s_barrier" ::: "memory");
    __builtin_amdgcn_s_setprio(1);
#pragma unroll
    for (int m = 0; m < 4; ++m)
#pragma unroll
      for (int n = 0; n < 2; ++n)
#pragma unroll
        for (int kk = 0; kk < 2; ++kk)
          acc[1][m][0][n] = __builtin_amdgcn_mfma_f32_16x16x32_f16(af[m][kk], bf0[n][kk], acc[1][m][0][n], 0, 0, 0);
    __builtin_amdgcn_s_setprio(0);
  }

  // ---------------- epilogue ----------------
  float bv[2][2];
#pragma unroll
  for (int nh = 0; nh < 2; ++nh)
#pragma unroll
    for (int n = 0; n < 2; ++n)
      bv[nh][n] = bias[Nblk + nh * 128 + wc * 32 + n * 16 + lr];

  if (nb >= 8) {
    // V block: write transposed into vt[(b*16+h)*64+d][s]
#pragma unroll
    for (int mh = 0; mh < 2; ++mh)
#pragma unroll
      for (int m = 0; m < 4; ++m)
#pragma unroll
        for (int nh = 0; nh < 2; ++nh)
#pragma unroll
          for (int n = 0; n < 2; ++n) {
            const int col = (int)Nblk + nh * 128 + wc * 32 + n * 16 + lr - 2048;
            const int hh = col >> 6, dd = col & 63;
            const size_t row = Mblk + mh * 128 + wr * 64 + m * 16 + lg * 4;
            const size_t bq = row >> 11, sq = row & 2047;
            f16x4_t o;
#pragma unroll
            for (int r = 0; r < 4; ++r) o[r] = (_Float16)(acc[mh][m][nh][n][r] + bv[nh][n]);
            *reinterpret_cast<f16x4_t*>(&vt[(((size_t)bq * HH + hh) * HDIM + dd) * SS + sq]) = o;
          }
  } else {
#pragma unroll
    for (int mh = 0; mh < 2; ++mh)
#pragma unroll
      for (int m = 0; m < 4; ++m)
#pragma unroll
        for (int nh = 0; nh < 2; ++nh)
#pragma unroll
          for (int n = 0; n < 2; ++n) {
            const size_t col = Nblk + nh * 128 + wc * 32 + n * 16 + lr;
            const size_t row0 = Mblk + mh * 128 + wr * 64 + m * 16 + lg * 4;
#pragma unroll
            for (int r = 0; r < 4; ++r)
              Cout[(row0 + r) * 2048 + col] = (_Float16)(acc[mh][m][nh][n][r] + bv[nh][n]);
          }
  }
}

// ---------------- out-proj NT GEMM (proven 128x128 structure, unchanged) ----------------
template <bool OUT_F32>
__global__ void gemm_nt(const _Float16* __restrict__ A, const _Float16* __restrict__ Bm,
                        const float* __restrict__ bias, void* __restrict__ Cout,
                        const int N, const int K, const int ldc, _Float16* __restrict__ vt) {
  constexpr int BK = 64;
  __shared__ _Float16 As[128 * BK];
  __shared__ _Float16 Bs[128 * BK];
  const int tid = threadIdx.x;
  const int wid = tid >> 6;
  const int lane = tid & 63;
  const int lr = lane & 15, lg = lane >> 4;
  const int wr = wid >> 1, wc = wid & 1;
  const size_t arow0 = (size_t)blockIdx.x * 128;
  const size_t bcol0 = (size_t)blockIdx.y * 128;

  f32x4_t acc[4][4] = {};

  const int srow = wid * 32 + (lane >> 3);
  const int scol = (lane & 7) * 8;
  const _Float16* Ag = A + (arow0 + srow) * (size_t)K + scol;
  const _Float16* Bg = Bm + (bcol0 + srow) * (size_t)K + scol;

  for (int kt = 0; kt < K; kt += BK) {
    __syncthreads();
#pragma unroll
    for (int c = 0; c < 4; ++c) {
      GLDS16(Ag + kt + (size_t)(c * 8) * K, &As[(wid * 32 + c * 8) * BK]);
      GLDS16(Bg + kt + (size_t)(c * 8) * K, &Bs[(wid * 32 + c * 8) * BK]);
    }
    __syncthreads();
#pragma unroll
    for (int kk = 0; kk < 2; ++kk) {
      f16x8_t af[4], bf[4];
#pragma unroll
      for (int mi = 0; mi < 4; ++mi)
        af[mi] = *reinterpret_cast<const f16x8_t*>(&As[(wr * 64 + mi * 16 + lr) * BK + kk * 32 + lg * 8]);
#pragma unroll
      for (int ni = 0; ni < 4; ++ni)
        bf[ni] = *reinterpret_cast<const f16x8_t*>(&Bs[(wc * 64 + ni * 16 + lr) * BK + kk * 32 + lg * 8]);
#pragma unroll
      for (int mi = 0; mi < 4; ++mi)
#pragma unroll
        for (int ni = 0; ni < 4; ++ni)
          acc[mi][ni] = __builtin_amdgcn_mfma_f32_16x16x32_f16(af[mi], bf[ni], acc[mi][ni], 0, 0, 0);
    }
  }

  float bv[4];
#pragma unroll
  for (int ni = 0; ni < 4; ++ni) bv[ni] = bias[bcol0 + wc * 64 + ni * 16 + lr];

#pragma unroll
  for (int mi = 0; mi < 4; ++mi)
#pragma unroll
    for (int ni = 0; ni < 4; ++ni)
#pragma unroll
      for (int r = 0; r < 4; ++r) {
        const size_t row = arow0 + wr * 64 + mi * 16 + lg * 4 + r;
        const size_t col = bcol0 + wc * 64 + ni * 16 + lr;
        const float v = acc[mi][ni][r] + bv[ni];
        if (OUT_F32) ((float*)Cout)[row * ldc + col] = v;
        else         ((_Float16*)Cout)[row * ldc + col] = (_Float16)v;
      }
}

// ---------------- banded flash attention v3 (unchanged) ----------------
__global__ void attn_kernel(const _Float16* __restrict__ qk, const _Float16* __restrict__ vt,
                            _Float16* __restrict__ ctx) {
  __shared__ _Float16 Ks[2][64 * 64];
  __shared__ _Float16 Vs[2][64 * 64];

  const int fid = blockIdx.x;
  const int nid = (fid & 7) * 256 + (fid >> 3);
  const int qt = nid & 31, h = (nid >> 5) & 15, b = nid >> 9;
  const int qs = qt * 64;
  const int tid = threadIdx.x, wid = tid >> 6, lane = tid & 63;
  const int lr = lane & 15, lg = lane >> 4;
  const int qrow0 = qs + wid * 16;

  const _Float16* qp = qk + (size_t)(b * SS + qrow0 + lr) * 2048 + h * HDIM + lg * 8;
  f16x8_t qf0 = *reinterpret_cast<const f16x8_t*>(qp);
  f16x8_t qf1 = *reinterpret_cast<const f16x8_t*>(qp + 32);
#pragma unroll
  for (int j = 0; j < 8; ++j) {
    qf0[j] = qf0[j] * (_Float16)0.125f;
    qf1[j] = qf1[j] * (_Float16)0.125f;
  }

  f32x4_t oaccT[4] = {};
  float lpart = 0.f;

  const int klo = max(0, qs - LEFTC);
  const int khi = min(SS, qs + 64 + LOOKA);
  const int nt = (khi - klo) >> 6;

  const int srow = lane >> 3;
  const int c16 = (lane & 7) ^ srow;
  const char* kbase = (const char*)qk + (size_t)(b * SS) * 4096 + 2048 + h * 128 + (size_t)c16 * 16;
  const char* vbase = (const char*)vt + ((size_t)(b * HH + h) * HDIM) * 4096 + (size_t)c16 * 16;

  auto stage = [&](int buf, int kt) {
#pragma unroll
    for (int i = 0; i < 2; ++i) {
      const int row = (wid * 2 + i) * 8 + srow;
      GLDS16(kbase + (size_t)(kt + row) * 4096, (char*)&Ks[buf][0] + (wid * 2 + i) * 1024);
      GLDS16(vbase + (size_t)row * 4096 + (size_t)kt * 2, (char*)&Vs[buf][0] + (wid * 2 + i) * 1024);
    }
  };

  stage(0, klo);
  __syncthreads();

  for (int t = 0; t < nt; ++t) {
    const int kt = klo + t * 64;
    const int cur = t & 1;
    if (t + 1 < nt) stage(cur ^ 1, klo + (t + 1) * 64);

    f32x4_t sacc[4] = {};
#pragma unroll
    for (int ki = 0; ki < 4; ++ki)
#pragma unroll
      for (int ks = 0; ks < 2; ++ks) {
        const f16x8_t kf = *reinterpret_cast<const f16x8_t*>(
            &Ks[cur][(ki * 16 + lr) * 64 + (((ks * 4 + lg) ^ (lr & 7)) * 8)]);
        sacc[ki] = __builtin_amdgcn_mfma_f32_16x16x32_f16(kf, ks == 0 ? qf0 : qf1, sacc[ki], 0, 0, 0);
      }

    const bool doMask = (t == 0 && qs >= LEFTC) || (t == nt - 1 && qs + 128 <= SS);
    if (doMask) {
      const int q = qrow0 + lr;
#pragma unroll
      for (int ki = 0; ki < 4; ++ki)
#pragma unroll
        for (int r = 0; r < 4; ++r) {
          const int key = kt + ki * 16 + lg * 4 + r;
          const bool ok = (key <= q + LOOKA) && (key + LEFTC >= q);
          sacc[ki][r] = ok ? sacc[ki][r] : -1e30f;
        }
    }

    f16x4_t pT[4];
#pragma unroll
    for (int ki = 0; ki < 4; ++ki)
#pragma unroll
      for (int r = 0; r < 4; ++r) {
        const float p = __expf(sacc[ki][r]);
        lpart += p;
        pT[ki][r] = (_Float16)p;
      }

#pragma unroll
    for (int ki = 0; ki < 4; ++ki)
#pragma unroll
      for (int di = 0; di < 4; ++di) {
        const f16x4_t vf = *reinterpret_cast<const f16x4_t*>(
            &Vs[cur][(di * 16 + lr) * 64 + ((((ki * 2 + (lg >> 1)) ^ (lr & 7)) << 3) + ((lg & 1) << 2))]);
        oaccT[di] = __builtin_amdgcn_mfma_f32_16x16x16f16(vf, pT[ki], oaccT[di], 0, 0, 0);
      }

    __syncthreads();
  }

  lpart += __shfl_xor(lpart, 16);
  lpart += __shfl_xor(lpart, 32);
  const float inv = 1.0f / lpart;
  const size_t orow = (size_t)(b * SS + qrow0 + lr) * DD + h * HDIM;
#pragma unroll
  for (int di = 0; di < 4; ++di) {
    f16x4_t o;
#pragma unroll
    for (int r = 0; r < 4; ++r) o[r] = (_Float16)(oaccT[di][r] * inv);
    *reinterpret_cast<f16x4_t*>(&ctx[orow + di * 16 + lg * 4]) = o;
  }
}

extern "C" void kernel_launch(void* const* d_in, const int* in_sizes, int n_in,
                              void* d_out, int out_size, void* d_ws, size_t ws_size,
                              hipStream_t stream) {
  const float* x     = (const float*)d_in[0];
  const float* W_in  = (const float*)d_in[1];
  const float* b_in  = (const float*)d_in[2];
  const float* W_out = (const float*)d_in[3];
  const float* b_out = (const float*)d_in[4];
  float* out = (float*)d_out;

  char* ws = (char*)d_ws;
  _Float16* xb   = (_Float16*)(ws);                        // 8192x1024  16 MB @ 0
  _Float16* wib  = (_Float16*)(ws + (16u << 20));          // 3072x1024   6 MB @ 16M
  _Float16* wob  = (_Float16*)(ws + (22u << 20));          // 1024x1024   2 MB @ 22M
  _Float16* qkb  = (_Float16*)(ws + (24u << 20));          // 8192x2048  32 MB @ 24M (Q|K)
  _Float16* ctxb = (_Float16*)(ws + (56u << 20));          // 8192x1024  16 MB @ 56M
  _Float16* vtb  = (_Float16*)(ws + (72u << 20));          // 64x64x2048 16 MB @ 72M (V^T)

  cvt_kernel<<<MROWS * DD / 1024, 256, 0, stream>>>(x, xb);
  cvt_kernel<<<N3D * DD / 1024, 256, 0, stream>>>(W_in, wib);
  cvt_kernel<<<DD * DD / 1024, 256, 0, stream>>>(W_out, wob);

  gemm_qkv8<<<dim3(32 * 12), 512, 0, stream>>>(xb, wib, b_in, qkb, vtb);
  attn_kernel<<<dim3(SS / 64 * HH * BB), 256, 0, stream>>>(qkb, vtb, ctxb);
  gemm_nt<true><<<dim3(MROWS / 128, DD / 128), 256, 0, stream>>>(ctxb, wob, b_out, out, DD, DD, DD, nullptr);
}

// Round 8
// 230.793 us; speedup vs baseline: 1.0403x; 1.0403x over previous
//
#include <hip/hip_runtime.h>
#include <hip/hip_fp16.h>

typedef _Float16 f16x4_t __attribute__((ext_vector_type(4)));
typedef _Float16 f16x8_t __attribute__((ext_vector_type(8)));
typedef float    f32x4_t __attribute__((ext_vector_type(4)));

#define GLDS16(gp, lp)                                                                   \
  __builtin_amdgcn_global_load_lds((const __attribute__((address_space(1))) void*)(gp),  \
                                   (__attribute__((address_space(3))) void*)(lp), 16, 0, 0)

constexpr int BB = 4, SS = 2048, DD = 1024, HH = 16, HDIM = 64;
constexpr int LOOKA = 64, LEFTC = 512;
constexpr int MROWS = BB * SS;   // 8192
constexpr int N3D = 3 * DD;      // 3072

// ---------------- fused f32 -> f16 convert: x | W_in | W_out in one launch ----------------
// sizes: 8388608 | 3145728 | 1048576 f32 elems; all segment boundaries 4-aligned.
__global__ void cvt_all_kernel(const float* __restrict__ x, const float* __restrict__ wi,
                               const float* __restrict__ wo, _Float16* __restrict__ xb,
                               _Float16* __restrict__ wib, _Float16* __restrict__ wob) {
  const int e = (blockIdx.x * 256 + threadIdx.x) * 4;
  const float* src;
  _Float16* dst;
  int off;
  if (e < 8388608)       { src = x;  dst = xb;  off = e; }
  else if (e < 11534336) { src = wi; dst = wib; off = e - 8388608; }
  else                   { src = wo; dst = wob; off = e - 11534336; }
  const float4 v = *reinterpret_cast<const float4*>(src + off);
  f16x4_t o;
  o[0] = (_Float16)v.x; o[1] = (_Float16)v.y; o[2] = (_Float16)v.z; o[3] = (_Float16)v.w;
  *reinterpret_cast<f16x4_t*>(dst + off) = o;
}

// ============ QKV GEMM: 256x256, BK=64, 8 waves — ROUND-5 PROVEN SCHEDULE ============
// (measured 68.8us / MfmaUtil 29 / 0 bank conflicts; round-7 reorder regressed -> reverted)
// Per tile T (slot s=T&1), 4 phases; 3x vmcnt(4) waits each retiring exactly the
// half-tiles the phase reads; stages write slot s^1 whose last readers are a full
// tile behind every barrier. Tail stages wrap to tile 0 (dummy, never read).
__global__ __launch_bounds__(512, 1) void gemm_qkv8(const _Float16* __restrict__ A,
                                                    const _Float16* __restrict__ Bm,
                                                    const float* __restrict__ bias,
                                                    _Float16* __restrict__ Cout,
                                                    _Float16* __restrict__ vt) {
  constexpr int BK = 64, NT = 1024 / BK;  // 16 K-tiles
  __shared__ _Float16 Ash[2][2][128 * 64];
  __shared__ _Float16 Bsh[2][2][128 * 64];

  // bijective XCD-chunked swizzle: 384 blocks, 48 per XCD
  const int bid = blockIdx.x;
  const int nid = (bid & 7) * 48 + (bid >> 3);
  const int mb = nid / 12, nb = nid % 12;
  const size_t Mblk = (size_t)mb * 256, Nblk = (size_t)nb * 256;

  const int tid = threadIdx.x;
  const int w = tid >> 6, lane = tid & 63;
  const int lr = lane & 15, lg = lane >> 4;
  const int wr = w >> 2;   // 0..1 (M)
  const int wc = w & 3;    // 0..3 (N)

  // staging: region row = i*64 + w*8 + (lane>>3); global chunk = (lane&7)^(lane>>3)
  const int rw = w * 8 + (lane >> 3);
  const int cg = (lane & 7) ^ (lane >> 3);
  const _Float16* Ag = A + (Mblk + rw) * 1024 + cg * 8;
  const _Float16* Bg = Bm + (Nblk + rw) * 1024 + cg * 8;

  auto stageA = [&](int t, int h) {
    const int s = t & 1;
    const int kt = (t & (NT - 1)) * BK;
#pragma unroll
    for (int i = 0; i < 2; ++i)
      GLDS16(Ag + (size_t)(h * 128 + i * 64) * 1024 + kt,
             (char*)&Ash[s][h][0] + w * 1024 + i * 8192);
  };
  auto stageB = [&](int t, int h) {
    const int s = t & 1;
    const int kt = (t & (NT - 1)) * BK;
#pragma unroll
    for (int i = 0; i < 2; ++i)
      GLDS16(Bg + (size_t)(h * 128 + i * 64) * 1024 + kt,
             (char*)&Bsh[s][h][0] + w * 1024 + i * 8192);
  };

  f32x4_t acc[2][4][2][2] = {};  // [mh][mi4][nh][ni2]
  f16x8_t af[4][2], bf0[2][2], bf1[2][2];

  const int axr = (wr * 64 + lr) * 64;
  const int bxr = (wc * 32 + lr) * 64;
  const int c0 = (lg ^ (lr & 7)) * 8;
  const int c1 = ((4 + lg) ^ (lr & 7)) * 8;

  // prologue: tile 0's four halves in issue order A0,B0,B1,A1
  stageA(0, 0);
  stageB(0, 0);
  stageB(0, 1);
  stageA(0, 1);

  for (int T = 0; T < NT; ++T) {
    const int s = T & 1;

    // ---------- phase 0: quadrant (0,0) ----------
    asm volatile("s_waitcnt vmcnt(4)" ::: "memory");  // A0,B0 of tile T landed
    asm volatile("s_barrier" ::: "memory");
#pragma unroll
    for (int m = 0; m < 4; ++m) {
      af[m][0] = *reinterpret_cast<const f16x8_t*>(&Ash[s][0][axr + m * 1024 + c0]);
      af[m][1] = *reinterpret_cast<const f16x8_t*>(&Ash[s][0][axr + m * 1024 + c1]);
    }
#pragma unroll
    for (int n = 0; n < 2; ++n) {
      bf0[n][0] = *reinterpret_cast<const f16x8_t*>(&Bsh[s][0][bxr + n * 1024 + c0]);
      bf0[n][1] = *reinterpret_cast<const f16x8_t*>(&Bsh[s][0][bxr + n * 1024 + c1]);
    }
    stageA(T + 1, 0);
    __builtin_amdgcn_s_setprio(1);
#pragma unroll
    for (int m = 0; m < 4; ++m)
#pragma unroll
      for (int n = 0; n < 2; ++n)
#pragma unroll
        for (int kk = 0; kk < 2; ++kk)
          acc[0][m][0][n] = __builtin_amdgcn_mfma_f32_16x16x32_f16(af[m][kk], bf0[n][kk], acc[0][m][0][n], 0, 0, 0);
    __builtin_amdgcn_s_setprio(0);

    // ---------- phase 1: quadrant (0,1) ----------
    asm volatile("s_waitcnt vmcnt(4)" ::: "memory");  // B1 of tile T landed
    asm volatile("s_barrier" ::: "memory");
#pragma unroll
    for (int n = 0; n < 2; ++n) {
      bf1[n][0] = *reinterpret_cast<const f16x8_t*>(&Bsh[s][1][bxr + n * 1024 + c0]);
      bf1[n][1] = *reinterpret_cast<const f16x8_t*>(&Bsh[s][1][bxr + n * 1024 + c1]);
    }
    stageB(T + 1, 0);
    __builtin_amdgcn_s_setprio(1);
#pragma unroll
    for (int m = 0; m < 4; ++m)
#pragma unroll
      for (int n = 0; n < 2; ++n)
#pragma unroll
        for (int kk = 0; kk < 2; ++kk)
          acc[0][m][1][n] = __builtin_amdgcn_mfma_f32_16x16x32_f16(af[m][kk], bf1[n][kk], acc[0][m][1][n], 0, 0, 0);
    __builtin_amdgcn_s_setprio(0);

    // ---------- phase 2: quadrant (1,1) ----------
    asm volatile("s_waitcnt vmcnt(4)" ::: "memory");  // A1 of tile T landed
    asm volatile("s_barrier" ::: "memory");
#pragma unroll
    for (int m = 0; m < 4; ++m) {
      af[m][0] = *reinterpret_cast<const f16x8_t*>(&Ash[s][1][axr + m * 1024 + c0]);
      af[m][1] = *reinterpret_cast<const f16x8_t*>(&Ash[s][1][axr + m * 1024 + c1]);
    }
    stageB(T + 1, 1);
    __builtin_amdgcn_s_setprio(1);
#pragma unroll
    for (int m = 0; m < 4; ++m)
#pragma unroll
      for (int n = 0; n < 2; ++n)
#pragma unroll
        for (int kk = 0; kk < 2; ++kk)
          acc[1][m][1][n] = __builtin_amdgcn_mfma_f32_16x16x32_f16(af[m][kk], bf1[n][kk], acc[1][m][1][n], 0, 0, 0);
    __builtin_amdgcn_s_setprio(0);

    // ---------- phase 3: quadrant (1,0) ---------- (frags already in regs)
    asm volatile("s_barrier" ::: "memory");
    stageA(T + 1, 1);
    __builtin_amdgcn_s_setprio(1);
#pragma unroll
    for (int m = 0; m < 4; ++m)
#pragma unroll
      for (int n = 0; n < 2; ++n)
#pragma unroll
        for (int kk = 0; kk < 2; ++kk)
          acc[1][m][0][n] = __builtin_amdgcn_mfma_f32_16x16x32_f16(af[m][kk], bf0[n][kk], acc[1][m][0][n], 0, 0, 0);
    __builtin_amdgcn_s_setprio(0);
  }

  // ---------------- epilogue ----------------
  float bv[2][2];
#pragma unroll
  for (int nh = 0; nh < 2; ++nh)
#pragma unroll
    for (int n = 0; n < 2; ++n)
      bv[nh][n] = bias[Nblk + nh * 128 + wc * 32 + n * 16 + lr];

  if (nb >= 8) {
    // V block: write transposed into vt[(b*16+h)*64+d][s]
#pragma unroll
    for (int mh = 0; mh < 2; ++mh)
#pragma unroll
      for (int m = 0; m < 4; ++m)
#pragma unroll
        for (int nh = 0; nh < 2; ++nh)
#pragma unroll
          for (int n = 0; n < 2; ++n) {
            const int col = (int)Nblk + nh * 128 + wc * 32 + n * 16 + lr - 2048;
            const int hh = col >> 6, dd = col & 63;
            const size_t row = Mblk + mh * 128 + wr * 64 + m * 16 + lg * 4;
            const size_t bq = row >> 11, sq = row & 2047;
            f16x4_t o;
#pragma unroll
            for (int r = 0; r < 4; ++r) o[r] = (_Float16)(acc[mh][m][nh][n][r] + bv[nh][n]);
            *reinterpret_cast<f16x4_t*>(&vt[(((size_t)bq * HH + hh) * HDIM + dd) * SS + sq]) = o;
          }
  } else {
#pragma unroll
    for (int mh = 0; mh < 2; ++mh)
#pragma unroll
      for (int m = 0; m < 4; ++m)
#pragma unroll
        for (int nh = 0; nh < 2; ++nh)
#pragma unroll
          for (int n = 0; n < 2; ++n) {
            const size_t col = Nblk + nh * 128 + wc * 32 + n * 16 + lr;
            const size_t row0 = Mblk + mh * 128 + wr * 64 + m * 16 + lg * 4;
#pragma unroll
            for (int r = 0; r < 4; ++r)
              Cout[(row0 + r) * 2048 + col] = (_Float16)(acc[mh][m][nh][n][r] + bv[nh][n]);
          }
  }
}

// ---------------- out-proj NT GEMM (proven 128x128 structure, unchanged) ----------------
template <bool OUT_F32>
__global__ void gemm_nt(const _Float16* __restrict__ A, const _Float16* __restrict__ Bm,
                        const float* __restrict__ bias, void* __restrict__ Cout,
                        const int N, const int K, const int ldc, _Float16* __restrict__ vt) {
  constexpr int BK = 64;
  __shared__ _Float16 As[128 * BK];
  __shared__ _Float16 Bs[128 * BK];
  const int tid = threadIdx.x;
  const int wid = tid >> 6;
  const int lane = tid & 63;
  const int lr = lane & 15, lg = lane >> 4;
  const int wr = wid >> 1, wc = wid & 1;
  const size_t arow0 = (size_t)blockIdx.x * 128;
  const size_t bcol0 = (size_t)blockIdx.y * 128;

  f32x4_t acc[4][4] = {};

  const int srow = wid * 32 + (lane >> 3);
  const int scol = (lane & 7) * 8;
  const _Float16* Ag = A + (arow0 + srow) * (size_t)K + scol;
  const _Float16* Bg = Bm + (bcol0 + srow) * (size_t)K + scol;

  for (int kt = 0; kt < K; kt += BK) {
    __syncthreads();
#pragma unroll
    for (int c = 0; c < 4; ++c) {
      GLDS16(Ag + kt + (size_t)(c * 8) * K, &As[(wid * 32 + c * 8) * BK]);
      GLDS16(Bg + kt + (size_t)(c * 8) * K, &Bs[(wid * 32 + c * 8) * BK]);
    }
    __syncthreads();
#pragma unroll
    for (int kk = 0; kk < 2; ++kk) {
      f16x8_t af[4], bf[4];
#pragma unroll
      for (int mi = 0; mi < 4; ++mi)
        af[mi] = *reinterpret_cast<const f16x8_t*>(&As[(wr * 64 + mi * 16 + lr) * BK + kk * 32 + lg * 8]);
#pragma unroll
      for (int ni = 0; ni < 4; ++ni)
        bf[ni] = *reinterpret_cast<const f16x8_t*>(&Bs[(wc * 64 + ni * 16 + lr) * BK + kk * 32 + lg * 8]);
#pragma unroll
      for (int mi = 0; mi < 4; ++mi)
#pragma unroll
        for (int ni = 0; ni < 4; ++ni)
          acc[mi][ni] = __builtin_amdgcn_mfma_f32_16x16x32_f16(af[mi], bf[ni], acc[mi][ni], 0, 0, 0);
    }
  }

  float bv[4];
#pragma unroll
  for (int ni = 0; ni < 4; ++ni) bv[ni] = bias[bcol0 + wc * 64 + ni * 16 + lr];

#pragma unroll
  for (int mi = 0; mi < 4; ++mi)
#pragma unroll
    for (int ni = 0; ni < 4; ++ni)
#pragma unroll
      for (int r = 0; r < 4; ++r) {
        const size_t row = arow0 + wr * 64 + mi * 16 + lg * 4 + r;
        const size_t col = bcol0 + wc * 64 + ni * 16 + lr;
        const float v = acc[mi][ni][r] + bv[ni];
        if (OUT_F32) ((float*)Cout)[row * ldc + col] = v;
        else         ((_Float16*)Cout)[row * ldc + col] = (_Float16)v;
      }
}

// ---------------- banded flash attention v3 (+ T5 setprio around MFMA clusters) ----------------
__global__ void attn_kernel(const _Float16* __restrict__ qk, const _Float16* __restrict__ vt,
                            _Float16* __restrict__ ctx) {
  __shared__ _Float16 Ks[2][64 * 64];
  __shared__ _Float16 Vs[2][64 * 64];

  const int fid = blockIdx.x;
  const int nid = (fid & 7) * 256 + (fid >> 3);
  const int qt = nid & 31, h = (nid >> 5) & 15, b = nid >> 9;
  const int qs = qt * 64;
  const int tid = threadIdx.x, wid = tid >> 6, lane = tid & 63;
  const int lr = lane & 15, lg = lane >> 4;
  const int qrow0 = qs + wid * 16;

  const _Float16* qp = qk + (size_t)(b * SS + qrow0 + lr) * 2048 + h * HDIM + lg * 8;
  f16x8_t qf0 = *reinterpret_cast<const f16x8_t*>(qp);
  f16x8_t qf1 = *reinterpret_cast<const f16x8_t*>(qp + 32);
#pragma unroll
  for (int j = 0; j < 8; ++j) {
    qf0[j] = qf0[j] * (_Float16)0.125f;
    qf1[j] = qf1[j] * (_Float16)0.125f;
  }

  f32x4_t oaccT[4] = {};
  float lpart = 0.f;

  const int klo = max(0, qs - LEFTC);
  const int khi = min(SS, qs + 64 + LOOKA);
  const int nt = (khi - klo) >> 6;

  const int srow = lane >> 3;
  const int c16 = (lane & 7) ^ srow;
  const char* kbase = (const char*)qk + (size_t)(b * SS) * 4096 + 2048 + h * 128 + (size_t)c16 * 16;
  const char* vbase = (const char*)vt + ((size_t)(b * HH + h) * HDIM) * 4096 + (size_t)c16 * 16;

  auto stage = [&](int buf, int kt) {
#pragma unroll
    for (int i = 0; i < 2; ++i) {
      const int row = (wid * 2 + i) * 8 + srow;
      GLDS16(kbase + (size_t)(kt + row) * 4096, (char*)&Ks[buf][0] + (wid * 2 + i) * 1024);
      GLDS16(vbase + (size_t)row * 4096 + (size_t)kt * 2, (char*)&Vs[buf][0] + (wid * 2 + i) * 1024);
    }
  };

  stage(0, klo);
  __syncthreads();

  for (int t = 0; t < nt; ++t) {
    const int kt = klo + t * 64;
    const int cur = t & 1;
    if (t + 1 < nt) stage(cur ^ 1, klo + (t + 1) * 64);

    f32x4_t sacc[4] = {};
    __builtin_amdgcn_s_setprio(1);
#pragma unroll
    for (int ki = 0; ki < 4; ++ki)
#pragma unroll
      for (int ks = 0; ks < 2; ++ks) {
        const f16x8_t kf = *reinterpret_cast<const f16x8_t*>(
            &Ks[cur][(ki * 16 + lr) * 64 + (((ks * 4 + lg) ^ (lr & 7)) * 8)]);
        sacc[ki] = __builtin_amdgcn_mfma_f32_16x16x32_f16(kf, ks == 0 ? qf0 : qf1, sacc[ki], 0, 0, 0);
      }
    __builtin_amdgcn_s_setprio(0);

    const bool doMask = (t == 0 && qs >= LEFTC) || (t == nt - 1 && qs + 128 <= SS);
    if (doMask) {
      const int q = qrow0 + lr;
#pragma unroll
      for (int ki = 0; ki < 4; ++ki)
#pragma unroll
        for (int r = 0; r < 4; ++r) {
          const int key = kt + ki * 16 + lg * 4 + r;
          const bool ok = (key <= q + LOOKA) && (key + LEFTC >= q);
          sacc[ki][r] = ok ? sacc[ki][r] : -1e30f;
        }
    }

    f16x4_t pT[4];
#pragma unroll
    for (int ki = 0; ki < 4; ++ki)
#pragma unroll
      for (int r = 0; r < 4; ++r) {
        const float p = __expf(sacc[ki][r]);
        lpart += p;
        pT[ki][r] = (_Float16)p;
      }

    __builtin_amdgcn_s_setprio(1);
#pragma unroll
    for (int ki = 0; ki < 4; ++ki)
#pragma unroll
      for (int di = 0; di < 4; ++di) {
        const f16x4_t vf = *reinterpret_cast<const f16x4_t*>(
            &Vs[cur][(di * 16 + lr) * 64 + ((((ki * 2 + (lg >> 1)) ^ (lr & 7)) << 3) + ((lg & 1) << 2))]);
        oaccT[di] = __builtin_amdgcn_mfma_f32_16x16x16f16(vf, pT[ki], oaccT[di], 0, 0, 0);
      }
    __builtin_amdgcn_s_setprio(0);

    __syncthreads();
  }

  lpart += __shfl_xor(lpart, 16);
  lpart += __shfl_xor(lpart, 32);
  const float inv = 1.0f / lpart;
  const size_t orow = (size_t)(b * SS + qrow0 + lr) * DD + h * HDIM;
#pragma unroll
  for (int di = 0; di < 4; ++di) {
    f16x4_t o;
#pragma unroll
    for (int r = 0; r < 4; ++r) o[r] = (_Float16)(oaccT[di][r] * inv);
    *reinterpret_cast<f16x4_t*>(&ctx[orow + di * 16 + lg * 4]) = o;
  }
}

extern "C" void kernel_launch(void* const* d_in, const int* in_sizes, int n_in,
                              void* d_out, int out_size, void* d_ws, size_t ws_size,
                              hipStream_t stream) {
  const float* x     = (const float*)d_in[0];
  const float* W_in  = (const float*)d_in[1];
  const float* b_in  = (const float*)d_in[2];
  const float* W_out = (const float*)d_in[3];
  const float* b_out = (const float*)d_in[4];
  float* out = (float*)d_out;

  char* ws = (char*)d_ws;
  _Float16* xb   = (_Float16*)(ws);                        // 8192x1024  16 MB @ 0
  _Float16* wib  = (_Float16*)(ws + (16u << 20));          // 3072x1024   6 MB @ 16M
  _Float16* wob  = (_Float16*)(ws + (22u << 20));          // 1024x1024   2 MB @ 22M
  _Float16* qkb  = (_Float16*)(ws + (24u << 20));          // 8192x2048  32 MB @ 24M (Q|K)
  _Float16* ctxb = (_Float16*)(ws + (56u << 20));          // 8192x1024  16 MB @ 56M
  _Float16* vtb  = (_Float16*)(ws + (72u << 20));          // 64x64x2048 16 MB @ 72M (V^T)

  cvt_all_kernel<<<12288, 256, 0, stream>>>(x, W_in, W_out, xb, wib, wob);
  gemm_qkv8<<<dim3(32 * 12), 512, 0, stream>>>(xb, wib, b_in, qkb, vtb);
  attn_kernel<<<dim3(SS / 64 * HH * BB), 256, 0, stream>>>(qkb, vtb, ctxb);
  gemm_nt<true><<<dim3(MROWS / 128, DD / 128), 256, 0, stream>>>(ctxb, wob, b_out, out, DD, DD, DD, nullptr);
}

// Round 10
// 227.841 us; speedup vs baseline: 1.0538x; 1.0130x over previous
//
#include <hip/hip_runtime.h>
#include <hip/hip_fp16.h>

typedef _Float16 f16x4_t __attribute__((ext_vector_type(4)));
typedef _Float16 f16x8_t __attribute__((ext_vector_type(8)));
typedef float    f32x4_t __attribute__((ext_vector_type(4)));

#define GLDS16(gp, lp)                                                                   \
  __builtin_amdgcn_global_load_lds((const __attribute__((address_space(1))) void*)(gp),  \
                                   (__attribute__((address_space(3))) void*)(lp), 16, 0, 0)

constexpr int BB = 4, SS = 2048, DD = 1024, HH = 16, HDIM = 64;
constexpr int LOOKA = 64, LEFTC = 512;
constexpr int MROWS = BB * SS;   // 8192
constexpr int N3D = 3 * DD;      // 3072

// ---------------- fused f32 -> f16 convert: x | W_in | W_out in one launch ----------------
__global__ void cvt_all_kernel(const float* __restrict__ x, const float* __restrict__ wi,
                               const float* __restrict__ wo, _Float16* __restrict__ xb,
                               _Float16* __restrict__ wib, _Float16* __restrict__ wob) {
  const int e = (blockIdx.x * 256 + threadIdx.x) * 4;
  const float* src;
  _Float16* dst;
  int off;
  if (e < 8388608)       { src = x;  dst = xb;  off = e; }
  else if (e < 11534336) { src = wi; dst = wib; off = e - 8388608; }
  else                   { src = wo; dst = wob; off = e - 11534336; }
  const float4 v = *reinterpret_cast<const float4*>(src + off);
  f16x4_t o;
  o[0] = (_Float16)v.x; o[1] = (_Float16)v.y; o[2] = (_Float16)v.z; o[3] = (_Float16)v.w;
  *reinterpret_cast<f16x4_t*>(dst + off) = o;
}

// ============ QKV GEMM: 256x256, BK=64, 8 waves — v4 schedule ============
// Round-5 proven read placement (reads AFTER wait->barrier), stages moved early:
//   ph0: vmcnt(4) bar | read A0,B0 | stage A0',B0' | MFMA(0,0)
//   ph1: vmcnt(4) bar | read B1    | stage B1',A1' | MFMA(0,1)
//   ph2: (no wait/bar) read A1 (landed@ph1 wait, ordered@ph1 bar) | MFMA(1,1)
//   ph3: (no wait/bar) MFMA(1,0)  [frags in regs]
// Invariant entering ph0(T): in-flight = tile T's 8 loads (oldest: A0,B0).
// Prefetch distance 4-5 phases; 2 waits + 2 barriers per tile (was 3+4).
// WAR: ph0(T+1) stages write regions whose last readers ran >=2 phases before
// ph0(T+1)'s barrier. Tail stages wrap to tile 0 (dummy, never read).
__global__ __launch_bounds__(512, 1) void gemm_qkv8(const _Float16* __restrict__ A,
                                                    const _Float16* __restrict__ Bm,
                                                    const float* __restrict__ bias,
                                                    _Float16* __restrict__ Cout,
                                                    _Float16* __restrict__ vt) {
  constexpr int BK = 64, NT = 1024 / BK;  // 16 K-tiles
  __shared__ _Float16 Ash[2][2][128 * 64];
  __shared__ _Float16 Bsh[2][2][128 * 64];

  // bijective XCD-chunked swizzle: 384 blocks, 48 per XCD
  const int bid = blockIdx.x;
  const int nid = (bid & 7) * 48 + (bid >> 3);
  const int mb = nid / 12, nb = nid % 12;
  const size_t Mblk = (size_t)mb * 256, Nblk = (size_t)nb * 256;

  const int tid = threadIdx.x;
  const int w = tid >> 6, lane = tid & 63;
  const int lr = lane & 15, lg = lane >> 4;
  const int wr = w >> 2;   // 0..1 (M)
  const int wc = w & 3;    // 0..3 (N)

  // staging: region row = i*64 + w*8 + (lane>>3); global chunk = (lane&7)^(lane>>3)
  const int rw = w * 8 + (lane >> 3);
  const int cg = (lane & 7) ^ (lane >> 3);
  const _Float16* Ag = A + (Mblk + rw) * 1024 + cg * 8;
  const _Float16* Bg = Bm + (Nblk + rw) * 1024 + cg * 8;

  auto stageA = [&](int t, int h) {
    const int s = t & 1;
    const int kt = (t & (NT - 1)) * BK;
#pragma unroll
    for (int i = 0; i < 2; ++i)
      GLDS16(Ag + (size_t)(h * 128 + i * 64) * 1024 + kt,
             (char*)&Ash[s][h][0] + w * 1024 + i * 8192);
  };
  auto stageB = [&](int t, int h) {
    const int s = t & 1;
    const int kt = (t & (NT - 1)) * BK;
#pragma unroll
    for (int i = 0; i < 2; ++i)
      GLDS16(Bg + (size_t)(h * 128 + i * 64) * 1024 + kt,
             (char*)&Bsh[s][h][0] + w * 1024 + i * 8192);
  };

  f32x4_t acc[2][4][2][2] = {};  // [mh][mi4][nh][ni2]
  f16x8_t af[4][2], bf0[2][2], bf1[2][2];

  const int axr = (wr * 64 + lr) * 64;
  const int bxr = (wc * 32 + lr) * 64;
  const int c0 = (lg ^ (lr & 7)) * 8;
  const int c1 = ((4 + lg) ^ (lr & 7)) * 8;

  // prologue: exactly tile 0's four halves, oldest-first A0,B0,B1,A1
  stageA(0, 0);
  stageB(0, 0);
  stageB(0, 1);
  stageA(0, 1);

  for (int T = 0; T < NT; ++T) {
    const int s = T & 1;

    // ---------- phase 0: quadrant (0,0) ----------
    asm volatile("s_waitcnt vmcnt(4)" ::: "memory");  // A0(T),B0(T) landed (per-wave)
    asm volatile("s_barrier" ::: "memory");           // -> landed for ALL waves
#pragma unroll
    for (int m = 0; m < 4; ++m) {
      af[m][0] = *reinterpret_cast<const f16x8_t*>(&Ash[s][0][axr + m * 1024 + c0]);
      af[m][1] = *reinterpret_cast<const f16x8_t*>(&Ash[s][0][axr + m * 1024 + c1]);
    }
#pragma unroll
    for (int n = 0; n < 2; ++n) {
      bf0[n][0] = *reinterpret_cast<const f16x8_t*>(&Bsh[s][0][bxr + n * 1024 + c0]);
      bf0[n][1] = *reinterpret_cast<const f16x8_t*>(&Bsh[s][0][bxr + n * 1024 + c1]);
    }
    stageA(T + 1, 0);
    stageB(T + 1, 0);
    __builtin_amdgcn_s_setprio(1);
#pragma unroll
    for (int m = 0; m < 4; ++m)
#pragma unroll
      for (int n = 0; n < 2; ++n)
#pragma unroll
        for (int kk = 0; kk < 2; ++kk)
          acc[0][m][0][n] = __builtin_amdgcn_mfma_f32_16x16x32_f16(af[m][kk], bf0[n][kk], acc[0][m][0][n], 0, 0, 0);
    __builtin_amdgcn_s_setprio(0);

    // ---------- phase 1: quadrant (0,1) ----------
    asm volatile("s_waitcnt vmcnt(4)" ::: "memory");  // B1(T),A1(T) landed
    asm volatile("s_barrier" ::: "memory");
#pragma unroll
    for (int n = 0; n < 2; ++n) {
      bf1[n][0] = *reinterpret_cast<const f16x8_t*>(&Bsh[s][1][bxr + n * 1024 + c0]);
      bf1[n][1] = *reinterpret_cast<const f16x8_t*>(&Bsh[s][1][bxr + n * 1024 + c1]);
    }
    stageB(T + 1, 1);
    stageA(T + 1, 1);
    __builtin_amdgcn_s_setprio(1);
#pragma unroll
    for (int m = 0; m < 4; ++m)
#pragma unroll
      for (int n = 0; n < 2; ++n)
#pragma unroll
        for (int kk = 0; kk < 2; ++kk)
          acc[0][m][1][n] = __builtin_amdgcn_mfma_f32_16x16x32_f16(af[m][kk], bf1[n][kk], acc[0][m][1][n], 0, 0, 0);
    __builtin_amdgcn_s_setprio(0);

    // ---------- phase 2: quadrant (1,1) ---------- (A1 landed@ph1 wait, ordered@ph1 bar)
#pragma unroll
    for (int m = 0; m < 4; ++m) {
      af[m][0] = *reinterpret_cast<const f16x8_t*>(&Ash[s][1][axr + m * 1024 + c0]);
      af[m][1] = *reinterpret_cast<const f16x8_t*>(&Ash[s][1][axr + m * 1024 + c1]);
    }
    __builtin_amdgcn_s_setprio(1);
#pragma unroll
    for (int m = 0; m < 4; ++m)
#pragma unroll
      for (int n = 0; n < 2; ++n)
#pragma unroll
        for (int kk = 0; kk < 2; ++kk)
          acc[1][m][1][n] = __builtin_amdgcn_mfma_f32_16x16x32_f16(af[m][kk], bf1[n][kk], acc[1][m][1][n], 0, 0, 0);
    __builtin_amdgcn_s_setprio(0);

    // ---------- phase 3: quadrant (1,0) ---------- (frags in regs; no wait/barrier)
    __builtin_amdgcn_s_setprio(1);
#pragma unroll
    for (int m = 0; m < 4; ++m)
#pragma unroll
      for (int n = 0; n < 2; ++n)
#pragma unroll
        for (int kk = 0; kk < 2; ++kk)
          acc[1][m][0][n] = __builtin_amdgcn_mfma_f32_16x16x32_f16(af[m][kk], bf0[n][kk], acc[1][m][0][n], 0, 0, 0);
    __builtin_amdgcn_s_setprio(0);
  }

  // ---------------- epilogue ----------------
  float bv[2][2];
#pragma unroll
  for (int nh = 0; nh < 2; ++nh)
#pragma unroll
    for (int n = 0; n < 2; ++n)
      bv[nh][n] = bias[Nblk + nh * 128 + wc * 32 + n * 16 + lr];

  if (nb >= 8) {
    // V block: write transposed into vt[(b*16+h)*64+d][s]
#pragma unroll
    for (int mh = 0; mh < 2; ++mh)
#pragma unroll
      for (int m = 0; m < 4; ++m)
#pragma unroll
        for (int nh = 0; nh < 2; ++nh)
#pragma unroll
          for (int n = 0; n < 2; ++n) {
            const int col = (int)Nblk + nh * 128 + wc * 32 + n * 16 + lr - 2048;
            const int hh = col >> 6, dd = col & 63;
            const size_t row = Mblk + mh * 128 + wr * 64 + m * 16 + lg * 4;
            const size_t bq = row >> 11, sq = row & 2047;
            f16x4_t o;
#pragma unroll
            for (int r = 0; r < 4; ++r) o[r] = (_Float16)(acc[mh][m][nh][n][r] + bv[nh][n]);
            *reinterpret_cast<f16x4_t*>(&vt[(((size_t)bq * HH + hh) * HDIM + dd) * SS + sq]) = o;
          }
  } else {
#pragma unroll
    for (int mh = 0; mh < 2; ++mh)
#pragma unroll
      for (int m = 0; m < 4; ++m)
#pragma unroll
        for (int nh = 0; nh < 2; ++nh)
#pragma unroll
          for (int n = 0; n < 2; ++n) {
            const size_t col = Nblk + nh * 128 + wc * 32 + n * 16 + lr;
            const size_t row0 = Mblk + mh * 128 + wr * 64 + m * 16 + lg * 4;
#pragma unroll
            for (int r = 0; r < 4; ++r)
              Cout[(row0 + r) * 2048 + col] = (_Float16)(acc[mh][m][nh][n][r] + bv[nh][n]);
          }
  }
}

// ---------------- out-proj NT GEMM (proven 128x128 structure, unchanged) ----------------
template <bool OUT_F32>
__global__ void gemm_nt(const _Float16* __restrict__ A, const _Float16* __restrict__ Bm,
                        const float* __restrict__ bias, void* __restrict__ Cout,
                        const int N, const int K, const int ldc, _Float16* __restrict__ vt) {
  constexpr int BK = 64;
  __shared__ _Float16 As[128 * BK];
  __shared__ _Float16 Bs[128 * BK];
  const int tid = threadIdx.x;
  const int wid = tid >> 6;
  const int lane = tid & 63;
  const int lr = lane & 15, lg = lane >> 4;
  const int wr = wid >> 1, wc = wid & 1;
  const size_t arow0 = (size_t)blockIdx.x * 128;
  const size_t bcol0 = (size_t)blockIdx.y * 128;

  f32x4_t acc[4][4] = {};

  const int srow = wid * 32 + (lane >> 3);
  const int scol = (lane & 7) * 8;
  const _Float16* Ag = A + (arow0 + srow) * (size_t)K + scol;
  const _Float16* Bg = Bm + (bcol0 + srow) * (size_t)K + scol;

  for (int kt = 0; kt < K; kt += BK) {
    __syncthreads();
#pragma unroll
    for (int c = 0; c < 4; ++c) {
      GLDS16(Ag + kt + (size_t)(c * 8) * K, &As[(wid * 32 + c * 8) * BK]);
      GLDS16(Bg + kt + (size_t)(c * 8) * K, &Bs[(wid * 32 + c * 8) * BK]);
    }
    __syncthreads();
#pragma unroll
    for (int kk = 0; kk < 2; ++kk) {
      f16x8_t af[4], bf[4];
#pragma unroll
      for (int mi = 0; mi < 4; ++mi)
        af[mi] = *reinterpret_cast<const f16x8_t*>(&As[(wr * 64 + mi * 16 + lr) * BK + kk * 32 + lg * 8]);
#pragma unroll
      for (int ni = 0; ni < 4; ++ni)
        bf[ni] = *reinterpret_cast<const f16x8_t*>(&Bs[(wc * 64 + ni * 16 + lr) * BK + kk * 32 + lg * 8]);
#pragma unroll
      for (int mi = 0; mi < 4; ++mi)
#pragma unroll
        for (int ni = 0; ni < 4; ++ni)
          acc[mi][ni] = __builtin_amdgcn_mfma_f32_16x16x32_f16(af[mi], bf[ni], acc[mi][ni], 0, 0, 0);
    }
  }

  float bv[4];
#pragma unroll
  for (int ni = 0; ni < 4; ++ni) bv[ni] = bias[bcol0 + wc * 64 + ni * 16 + lr];

#pragma unroll
  for (int mi = 0; mi < 4; ++mi)
#pragma unroll
    for (int ni = 0; ni < 4; ++ni)
#pragma unroll
      for (int r = 0; r < 4; ++r) {
        const size_t row = arow0 + wr * 64 + mi * 16 + lg * 4 + r;
        const size_t col = bcol0 + wc * 64 + ni * 16 + lr;
        const float v = acc[mi][ni][r] + bv[ni];
        if (OUT_F32) ((float*)Cout)[row * ldc + col] = v;
        else         ((_Float16*)Cout)[row * ldc + col] = (_Float16)v;
      }
}

// ---------------- banded flash attention v3 (+ T5 setprio, unchanged) ----------------
__global__ void attn_kernel(const _Float16* __restrict__ qk, const _Float16* __restrict__ vt,
                            _Float16* __restrict__ ctx) {
  __shared__ _Float16 Ks[2][64 * 64];
  __shared__ _Float16 Vs[2][64 * 64];

  const int fid = blockIdx.x;
  const int nid = (fid & 7) * 256 + (fid >> 3);
  const int qt = nid & 31, h = (nid >> 5) & 15, b = nid >> 9;
  const int qs = qt * 64;
  const int tid = threadIdx.x, wid = tid >> 6, lane = tid & 63;
  const int lr = lane & 15, lg = lane >> 4;
  const int qrow0 = qs + wid * 16;

  const _Float16* qp = qk + (size_t)(b * SS + qrow0 + lr) * 2048 + h * HDIM + lg * 8;
  f16x8_t qf0 = *reinterpret_cast<const f16x8_t*>(qp);
  f16x8_t qf1 = *reinterpret_cast<const f16x8_t*>(qp + 32);
#pragma unroll
  for (int j = 0; j < 8; ++j) {
    qf0[j] = qf0[j] * (_Float16)0.125f;
    qf1[j] = qf1[j] * (_Float16)0.125f;
  }

  f32x4_t oaccT[4] = {};
  float lpart = 0.f;

  const int klo = max(0, qs - LEFTC);
  const int khi = min(SS, qs + 64 + LOOKA);
  const int nt = (khi - klo) >> 6;

  const int srow = lane >> 3;
  const int c16 = (lane & 7) ^ srow;
  const char* kbase = (const char*)qk + (size_t)(b * SS) * 4096 + 2048 + h * 128 + (size_t)c16 * 16;
  const char* vbase = (const char*)vt + ((size_t)(b * HH + h) * HDIM) * 4096 + (size_t)c16 * 16;

  auto stage = [&](int buf, int kt) {
#pragma unroll
    for (int i = 0; i < 2; ++i) {
      const int row = (wid * 2 + i) * 8 + srow;
      GLDS16(kbase + (size_t)(kt + row) * 4096, (char*)&Ks[buf][0] + (wid * 2 + i) * 1024);
      GLDS16(vbase + (size_t)row * 4096 + (size_t)kt * 2, (char*)&Vs[buf][0] + (wid * 2 + i) * 1024);
    }
  };

  stage(0, klo);
  __syncthreads();

  for (int t = 0; t < nt; ++t) {
    const int kt = klo + t * 64;
    const int cur = t & 1;
    if (t + 1 < nt) stage(cur ^ 1, klo + (t + 1) * 64);

    f32x4_t sacc[4] = {};
    __builtin_amdgcn_s_setprio(1);
#pragma unroll
    for (int ki = 0; ki < 4; ++ki)
#pragma unroll
      for (int ks = 0; ks < 2; ++ks) {
        const f16x8_t kf = *reinterpret_cast<const f16x8_t*>(
            &Ks[cur][(ki * 16 + lr) * 64 + (((ks * 4 + lg) ^ (lr & 7)) * 8)]);
        sacc[ki] = __builtin_amdgcn_mfma_f32_16x16x32_f16(kf, ks == 0 ? qf0 : qf1, sacc[ki], 0, 0, 0);
      }
    __builtin_amdgcn_s_setprio(0);

    const bool doMask = (t == 0 && qs >= LEFTC) || (t == nt - 1 && qs + 128 <= SS);
    if (doMask) {
      const int q = qrow0 + lr;
#pragma unroll
      for (int ki = 0; ki < 4; ++ki)
#pragma unroll
        for (int r = 0; r < 4; ++r) {
          const int key = kt + ki * 16 + lg * 4 + r;
          const bool ok = (key <= q + LOOKA) && (key + LEFTC >= q);
          sacc[ki][r] = ok ? sacc[ki][r] : -1e30f;
        }
    }

    f16x4_t pT[4];
#pragma unroll
    for (int ki = 0; ki < 4; ++ki)
#pragma unroll
      for (int r = 0; r < 4; ++r) {
        const float p = __expf(sacc[ki][r]);
        lpart += p;
        pT[ki][r] = (_Float16)p;
      }

    __builtin_amdgcn_s_setprio(1);
#pragma unroll
    for (int ki = 0; ki < 4; ++ki)
#pragma unroll
      for (int di = 0; di < 4; ++di) {
        const f16x4_t vf = *reinterpret_cast<const f16x4_t*>(
            &Vs[cur][(di * 16 + lr) * 64 + ((((ki * 2 + (lg >> 1)) ^ (lr & 7)) << 3) + ((lg & 1) << 2))]);
        oaccT[di] = __builtin_amdgcn_mfma_f32_16x16x16f16(vf, pT[ki], oaccT[di], 0, 0, 0);
      }
    __builtin_amdgcn_s_setprio(0);

    __syncthreads();
  }

  lpart += __shfl_xor(lpart, 16);
  lpart += __shfl_xor(lpart, 32);
  const float inv = 1.0f / lpart;
  const size_t orow = (size_t)(b * SS + qrow0 + lr) * DD + h * HDIM;
#pragma unroll
  for (int di = 0; di < 4; ++di) {
    f16x4_t o;
#pragma unroll
    for (int r = 0; r < 4; ++r) o[r] = (_Float16)(oaccT[di][r] * inv);
    *reinterpret_cast<f16x4_t*>(&ctx[orow + di * 16 + lg * 4]) = o;
  }
}

extern "C" void kernel_launch(void* const* d_in, const int* in_sizes, int n_in,
                              void* d_out, int out_size, void* d_ws, size_t ws_size,
                              hipStream_t stream) {
  const float* x     = (const float*)d_in[0];
  const float* W_in  = (const float*)d_in[1];
  const float* b_in  = (const float*)d_in[2];
  const float* W_out = (const float*)d_in[3];
  const float* b_out = (const float*)d_in[4];
  float* out = (float*)d_out;

  char* ws = (char*)d_ws;
  _Float16* xb   = (_Float16*)(ws);                        // 8192x1024  16 MB @ 0
  _Float16* wib  = (_Float16*)(ws + (16u << 20));          // 3072x1024   6 MB @ 16M
  _Float16* wob  = (_Float16*)(ws + (22u << 20));          // 1024x1024   2 MB @ 22M
  _Float16* qkb  = (_Float16*)(ws + (24u << 20));          // 8192x2048  32 MB @ 24M (Q|K)
  _Float16* ctxb = (_Float16*)(ws + (56u << 20));          // 8192x1024  16 MB @ 56M
  _Float16* vtb  = (_Float16*)(ws + (72u << 20));          // 64x64x2048 16 MB @ 72M (V^T)

  cvt_all_kernel<<<12288, 256, 0, stream>>>(x, W_in, W_out, xb, wib, wob);
  gemm_qkv8<<<dim3(32 * 12), 512, 0, stream>>>(xb, wib, b_in, qkb, vtb);
  attn_kernel<<<dim3(SS / 64 * HH * BB), 256, 0, stream>>>(qkb, vtb, ctxb);
  gemm_nt<true><<<dim3(MROWS / 128, DD / 128), 256, 0, stream>>>(ctxb, wob, b_out, out, DD, DD, DD, nullptr);
}